// Round 1
// baseline (47.613 us; speedup 1.0000x reference)
//
#include <hip/hip_runtime.h>

#define THREADS 256
#define NPTS 2048
#define PTS_PER_THREAD 2
// 2048 points / (256 threads * 2 pts) = 4 chunks per (dir,batch)
// grid = 2 dirs * 32 batches * 4 chunks = 256 blocks

__global__ __launch_bounds__(THREADS) void chamfer_kernel(
    const float* __restrict__ inst, const float* __restrict__ model,
    float* __restrict__ partial)
{
    __shared__ float4 sB[NPTS];   // (-2bx, -2by, -2bz, |b|^2)
    __shared__ float wsum[4];

    const int blk   = blockIdx.x;     // 0..255
    const int dir   = blk >> 7;       // 0: a=inst,b=model ; 1: swapped
    const int rem   = blk & 127;
    const int batch = rem >> 2;       // 0..31
    const int chunk = rem & 3;        // 0..3

    const float* __restrict__ A  = dir ? model : inst;
    const float* __restrict__ Bp = dir ? inst  : model;

    // Stage candidate set for this batch into LDS
    const float* bbase = Bp + (size_t)batch * NPTS * 3;
    for (int m = threadIdx.x; m < NPTS; m += THREADS) {
        float bx = bbase[m*3+0], by = bbase[m*3+1], bz = bbase[m*3+2];
        sB[m] = make_float4(-2.f*bx, -2.f*by, -2.f*bz,
                            fmaf(bx,bx, fmaf(by,by, bz*bz)));
    }
    __syncthreads();

    // My 2 query points
    const float* abase = A + (size_t)batch * NPTS * 3
                           + (size_t)chunk * (THREADS*PTS_PER_THREAD) * 3;
    const int i0 = threadIdx.x;
    const int i1 = threadIdx.x + THREADS;
    const float ax0 = abase[i0*3+0], ay0 = abase[i0*3+1], az0 = abase[i0*3+2];
    const float ax1 = abase[i1*3+0], ay1 = abase[i1*3+1], az1 = abase[i1*3+2];

    float mn0 = 3.4e38f, mn1 = 3.4e38f;
    #pragma unroll 8
    for (int m = 0; m < NPTS; ++m) {
        float4 bm = sB[m];  // broadcast ds_read_b128, conflict-free
        float t0 = fmaf(bm.z, az0, fmaf(bm.y, ay0, fmaf(bm.x, ax0, bm.w)));
        float t1 = fmaf(bm.z, az1, fmaf(bm.y, ay1, fmaf(bm.x, ax1, bm.w)));
        mn0 = fminf(mn0, t0);
        mn1 = fminf(mn1, t1);
    }
    const float a20 = fmaf(ax0,ax0, fmaf(ay0,ay0, az0*az0));
    const float a21 = fmaf(ax1,ax1, fmaf(ay1,ay1, az1*az1));
    float s = (mn0 + a20) + (mn1 + a21);

    // wave reduce (64 lanes) then cross-wave via LDS — fixed order, deterministic
    #pragma unroll
    for (int o = 32; o > 0; o >>= 1) s += __shfl_down(s, o, 64);
    const int lane = threadIdx.x & 63, wid = threadIdx.x >> 6;
    if (lane == 0) wsum[wid] = s;
    __syncthreads();
    if (threadIdx.x == 0) partial[blk] = (wsum[0] + wsum[1]) + (wsum[2] + wsum[3]);
}

#define NUM_PARTIAL 256
#define BATCH 32
#define NUM_CLASSES 6

__global__ __launch_bounds__(256) void finalize_kernel(
    const float* __restrict__ partial, const float* __restrict__ pred,
    const int* __restrict__ gt, float* __restrict__ out)
{
    __shared__ float s_ce[BATCH];
    __shared__ float wsum[4];
    const int tid = threadIdx.x;

    float v = partial[tid];
    #pragma unroll
    for (int o = 32; o > 0; o >>= 1) v += __shfl_down(v, o, 64);
    const int lane = tid & 63, wid = tid >> 6;
    if (lane == 0) wsum[wid] = v;

    if (tid < BATCH) {
        const float* row = pred + tid * NUM_CLASSES;
        float mx = row[0];
        #pragma unroll
        for (int c = 1; c < NUM_CLASSES; ++c) mx = fmaxf(mx, row[c]);
        float se = 0.f;
        #pragma unroll
        for (int c = 0; c < NUM_CLASSES; ++c) se += __expf(row[c] - mx);
        const int lbl = gt[tid];
        s_ce[tid] = -(row[lbl] - mx - __logf(se));
    }
    __syncthreads();

    if (tid == 0) {
        float cd_sum = (wsum[0] + wsum[1]) + (wsum[2] + wsum[3]);
        float cd = cd_sum / (float)(BATCH * NPTS);   // mean(dist1)+mean(dist2), N==M
        float ce = 0.f;
        for (int i = 0; i < BATCH; ++i) ce += s_ce[i];
        ce /= (float)BATCH;
        out[0] = 5.f * cd + ce;
        out[1] = cd;
        out[2] = ce;
    }
}

extern "C" void kernel_launch(void* const* d_in, const int* in_sizes, int n_in,
                              void* d_out, int out_size, void* d_ws, size_t ws_size,
                              hipStream_t stream) {
    const float* inst  = (const float*)d_in[0];
    const float* model = (const float*)d_in[1];
    const float* pred  = (const float*)d_in[2];
    const int*   gt    = (const int*)d_in[3];
    float* out     = (float*)d_out;
    float* partial = (float*)d_ws;   // 256 floats

    chamfer_kernel<<<NUM_PARTIAL, THREADS, 0, stream>>>(inst, model, partial);
    finalize_kernel<<<1, 256, 0, stream>>>(partial, pred, gt, out);
}

// Round 2
// 32.177 us; speedup vs baseline: 1.4797x; 1.4797x over previous
//
#include <hip/hip_runtime.h>

#define THREADS 256
#define NPTS 2048
#define BATCH 32
#define NUM_CLASSES 6
#define QPT 8   // queries per thread = 2048 / 256

// ---------------- Kernel 1: per-chunk partial min (+|a|^2 folded in) -------
// grid = 2 * 32 * C blocks. Block owns ALL 2048 queries of one (dir,batch)
// against a candidate chunk of 2048/C model points staged in LDS.
template<int C>
__global__ __launch_bounds__(THREADS) void chamfer_partial(
    const float* __restrict__ inst, const float* __restrict__ model,
    float* __restrict__ pmin)
{
    constexpr int CAND = NPTS / C;
    __shared__ float4 sB[CAND];   // (-2bx, -2by, -2bz, |b|^2)

    const int blk   = blockIdx.x;            // 0 .. 64*C-1
    const int dir   = blk / (BATCH * C);
    const int rem   = blk % (BATCH * C);
    const int batch = rem / C;
    const int c     = rem % C;

    const float* __restrict__ A  = dir ? model : inst;
    const float* __restrict__ Bp = dir ? inst  : model;

    const float* bbase = Bp + ((size_t)batch * NPTS + (size_t)c * CAND) * 3;
    for (int m = threadIdx.x; m < CAND; m += THREADS) {
        float bx = bbase[m*3+0], by = bbase[m*3+1], bz = bbase[m*3+2];
        sB[m] = make_float4(-2.f*bx, -2.f*by, -2.f*bz,
                            fmaf(bx,bx, fmaf(by,by, bz*bz)));
    }
    __syncthreads();

    const float* abase = A + (size_t)batch * NPTS * 3;
    float qx[QPT], qy[QPT], qz[QPT], mn[QPT];
    #pragma unroll
    for (int k = 0; k < QPT; ++k) {
        const int i = threadIdx.x + k * THREADS;
        qx[k] = abase[i*3+0]; qy[k] = abase[i*3+1]; qz[k] = abase[i*3+2];
        mn[k] = 3.4e38f;
    }

    #pragma unroll 4
    for (int m = 0; m < CAND; ++m) {
        const float4 bm = sB[m];   // broadcast ds_read_b128, amortized over 8 queries
        #pragma unroll
        for (int k = 0; k < QPT; ++k) {
            float t = fmaf(bm.z, qz[k], fmaf(bm.y, qy[k], fmaf(bm.x, qx[k], bm.w)));
            mn[k] = fminf(mn[k], t);
        }
    }

    float* obase = pmin + (size_t)blk * NPTS;
    #pragma unroll
    for (int k = 0; k < QPT; ++k) {
        const float a2 = fmaf(qx[k],qx[k], fmaf(qy[k],qy[k], qz[k]*qz[k]));
        obase[threadIdx.x + k*THREADS] = mn[k] + a2;   // min(x_c)+a2 == min(x_c+a2)
    }
}

// ---------------- Kernel 2: min across chunks + block partial sums ---------
// grid = 256. Block handles one quarter (512 queries) of one (dir,batch).
template<int C>
__global__ __launch_bounds__(256) void combine_kernel(
    const float* __restrict__ pmin, float* __restrict__ partial)
{
    const int p       = blockIdx.x >> 2;   // (dir*32+batch), 0..63
    const int quarter = blockIdx.x & 3;
    const int tid     = threadIdx.x;
    const float* base = pmin + (size_t)p * C * NPTS;

    float s = 0.f;
    #pragma unroll
    for (int k = 0; k < 2; ++k) {
        const int q = quarter * 512 + k * 256 + tid;
        float v = 3.4e38f;
        #pragma unroll
        for (int c = 0; c < C; ++c) v = fminf(v, base[(size_t)c * NPTS + q]);
        s += v;
    }
    #pragma unroll
    for (int o = 32; o > 0; o >>= 1) s += __shfl_down(s, o, 64);
    __shared__ float wsum[4];
    const int lane = tid & 63, wid = tid >> 6;
    if (lane == 0) wsum[wid] = s;
    __syncthreads();
    if (tid == 0) partial[blockIdx.x] = (wsum[0] + wsum[1]) + (wsum[2] + wsum[3]);
}

// ---------------- Kernel 3: final reduce + cross-entropy -------------------
__global__ __launch_bounds__(256) void finalize_kernel(
    const float* __restrict__ partial, const float* __restrict__ pred,
    const int* __restrict__ gt, float* __restrict__ out)
{
    __shared__ float s_ce[BATCH];
    __shared__ float wsum[4];
    const int tid = threadIdx.x;

    float v = partial[tid];
    #pragma unroll
    for (int o = 32; o > 0; o >>= 1) v += __shfl_down(v, o, 64);
    const int lane = tid & 63, wid = tid >> 6;
    if (lane == 0) wsum[wid] = v;

    if (tid < BATCH) {
        const float* row = pred + tid * NUM_CLASSES;
        float mx = row[0];
        #pragma unroll
        for (int c = 1; c < NUM_CLASSES; ++c) mx = fmaxf(mx, row[c]);
        float se = 0.f;
        #pragma unroll
        for (int c = 0; c < NUM_CLASSES; ++c) se += __expf(row[c] - mx);
        const int lbl = gt[tid];
        s_ce[tid] = -(row[lbl] - mx - __logf(se));
    }
    __syncthreads();

    if (tid == 0) {
        float cd_sum = (wsum[0] + wsum[1]) + (wsum[2] + wsum[3]);
        float cd = cd_sum / (float)(BATCH * NPTS);
        float ce = 0.f;
        for (int i = 0; i < BATCH; ++i) ce += s_ce[i];
        ce /= (float)BATCH;
        out[0] = 5.f * cd + ce;
        out[1] = cd;
        out[2] = ce;
    }
}

template<int C>
static void launch_pipeline(const float* inst, const float* model,
                            const float* pred, const int* gt,
                            float* out, float* ws, hipStream_t stream)
{
    float* pmin    = ws;                                  // 64*C*2048 floats
    float* partial = ws + (size_t)64 * C * NPTS;          // 256 floats
    chamfer_partial<C><<<64 * C, THREADS, 0, stream>>>(inst, model, pmin);
    combine_kernel<C><<<256, 256, 0, stream>>>(pmin, partial);
    finalize_kernel<<<1, 256, 0, stream>>>(partial, pred, gt, out);
}

extern "C" void kernel_launch(void* const* d_in, const int* in_sizes, int n_in,
                              void* d_out, int out_size, void* d_ws, size_t ws_size,
                              hipStream_t stream) {
    const float* inst  = (const float*)d_in[0];
    const float* model = (const float*)d_in[1];
    const float* pred  = (const float*)d_in[2];
    const int*   gt    = (const int*)d_in[3];
    float* out = (float*)d_out;
    float* ws  = (float*)d_ws;

    const size_t need8 = ((size_t)64 * 8 * NPTS + 256) * sizeof(float);
    const size_t need4 = ((size_t)64 * 4 * NPTS + 256) * sizeof(float);
    const size_t need2 = ((size_t)64 * 2 * NPTS + 256) * sizeof(float);
    const size_t need1 = ((size_t)64 * 1 * NPTS + 256) * sizeof(float);

    if      (ws_size >= need8) launch_pipeline<8>(inst, model, pred, gt, out, ws, stream);
    else if (ws_size >= need4) launch_pipeline<4>(inst, model, pred, gt, out, ws, stream);
    else if (ws_size >= need2) launch_pipeline<2>(inst, model, pred, gt, out, ws, stream);
    else                       launch_pipeline<1>(inst, model, pred, gt, out, ws, stream);
}

// Round 3
// 27.417 us; speedup vs baseline: 1.7366x; 1.1736x over previous
//
#include <hip/hip_runtime.h>

typedef __attribute__((ext_vector_type(8))) short short8;
typedef __attribute__((ext_vector_type(4))) float f32x4;

#define NPTS 2048
#define BATCH 32
#define NUM_CLASSES 6
#define THREADS 256
#define CTILES 128            // 2048/16 candidate tiles
#define QT 4                  // query tiles per wave (4 waves * 4 * 16 = 256 q/block)
#define CAND_BYTES (NPTS*32)  // 32 B per candidate (kg0 16B + kg1 16B)
#define ZOFF CAND_BYTES       // 16 B zero block for lanes 32-63 (k>=16 slots)

__device__ __forceinline__ unsigned short f2bf(float x) {
    union { float f; unsigned u; } v; v.f = x;
    unsigned r = v.u + 0x7FFF + ((v.u >> 16) & 1);   // RNE to bf16
    return (unsigned short)(r >> 16);
}
__device__ __forceinline__ float bf2f(unsigned short h) {
    union { unsigned u; float f; } v; v.u = ((unsigned)h) << 16; return v.f;
}

// grid = 512: blk -> dir (>>8), batch ((>>3)&31), qchunk (&7).
// Block: 256 queries vs all 2048 candidates of one (dir,batch).
// MFMA computes S = -2 a.b + b^2 ; per-query result = min_c S + a^2.
__global__ __launch_bounds__(THREADS) void chamfer_mfma(
    const float* __restrict__ inst, const float* __restrict__ model,
    float* __restrict__ partial)
{
    __shared__ char  cands[CAND_BYTES + 16];
    __shared__ float4 qs[THREADS];          // (x,y,z,a2) per query
    __shared__ float wsum[4];

    const int blk   = blockIdx.x;
    const int dir   = blk >> 8;
    const int batch = (blk >> 3) & 31;
    const int qc    = blk & 7;
    const int tid   = threadIdx.x;

    const float* __restrict__ Q = dir ? model : inst;
    const float* __restrict__ C = dir ? inst  : model;

    if (tid < 4) ((float*)(cands + ZOFF))[tid] = 0.f;

    // ---- stage candidates into B-frag layout ----
    // B[k][c]: k0-2=-2bh, k3-5=-2bh, k6-8=-2bl, k9=b2h, k10=b2l, rest 0
    const float* cb = C + (size_t)batch * NPTS * 3;
    for (int c = tid; c < NPTS; c += THREADS) {
        float bx = cb[c*3+0], by = cb[c*3+1], bz = cb[c*3+2];
        float m2x = -2.f*bx, m2y = -2.f*by, m2z = -2.f*bz;
        unsigned short hx = f2bf(m2x), hy = f2bf(m2y), hz = f2bf(m2z);
        unsigned short lx = f2bf(m2x - bf2f(hx));
        unsigned short ly = f2bf(m2y - bf2f(hy));
        unsigned short lz = f2bf(m2z - bf2f(hz));
        float b2 = fmaf(bx,bx, fmaf(by,by, bz*bz));
        unsigned short b2h = f2bf(b2);
        unsigned short b2l = f2bf(b2 - bf2f(b2h));
        short8 kg0 = { (short)hx,(short)hy,(short)hz,(short)hx,(short)hy,(short)hz,(short)lx,(short)ly };
        short8 kg1 = { (short)lz,(short)b2h,(short)b2l,0,0,0,0,0 };
        *(short8*)(cands + c*32)      = kg0;
        *(short8*)(cands + c*32 + 16) = kg1;
    }

    // ---- stage queries ----
    {
        const float* qb = Q + ((size_t)batch * NPTS + (size_t)qc * THREADS) * 3;
        float x = qb[tid*3+0], y = qb[tid*3+1], z = qb[tid*3+2];
        qs[tid] = make_float4(x, y, z, fmaf(x,x, fmaf(y,y, z*z)));
    }
    __syncthreads();

    const int lane = tid & 63, wid = tid >> 6;
    const int lg = lane >> 4, lc = lane & 15;

    // ---- A-frags: row = lane&15, k = (lane>>4)*8 + j ----
    // A[r][k]: k0-2=ah, k3-5=al, k6-8=ah, k9=1, k10=1, rest 0
    short8 af[QT];
    #pragma unroll
    for (int qt = 0; qt < QT; ++qt) {
        float4 q = qs[(wid*QT + qt)*16 + lc];
        unsigned short hx = f2bf(q.x), hy = f2bf(q.y), hz = f2bf(q.z);
        unsigned short lx = f2bf(q.x - bf2f(hx));
        unsigned short ly = f2bf(q.y - bf2f(hy));
        unsigned short lz = f2bf(q.z - bf2f(hz));
        short8 f;
        if (lg == 0)
            f = (short8){(short)hx,(short)hy,(short)hz,(short)lx,(short)ly,(short)lz,(short)hx,(short)hy};
        else if (lg == 1)
            f = (short8){(short)hz,(short)0x3F80,(short)0x3F80,0,0,0,0,0};
        else
            f = (short8){0,0,0,0,0,0,0,0};
        af[qt] = f;
    }

    // B-frag read address: lanes 0-31 real data, lanes 32-63 shared zero block
    int boff, bstride;
    if (lane < 32) { boff = lc*32 + lg*16; bstride = 512; }
    else           { boff = ZOFF;          bstride = 0;   }

    f32x4 mn[QT];
    #pragma unroll
    for (int qt = 0; qt < QT; ++qt) mn[qt] = (f32x4){3.4e38f,3.4e38f,3.4e38f,3.4e38f};

    const f32x4 zero4 = (f32x4){0.f,0.f,0.f,0.f};
    for (int ct = 0; ct < CTILES; ct += 2) {
        short8 b0 = *(const short8*)(cands + boff);
        short8 b1 = *(const short8*)(cands + boff + bstride);
        boff += 2*bstride;
        f32x4 aA[QT], aB[QT];
        #pragma unroll
        for (int qt = 0; qt < QT; ++qt)
            aA[qt] = __builtin_amdgcn_mfma_f32_16x16x32_bf16(af[qt], b0, zero4, 0,0,0);
        #pragma unroll
        for (int qt = 0; qt < QT; ++qt)
            aB[qt] = __builtin_amdgcn_mfma_f32_16x16x32_bf16(af[qt], b1, zero4, 0,0,0);
        #pragma unroll
        for (int qt = 0; qt < QT; ++qt)
            #pragma unroll
            for (int r = 0; r < 4; ++r)
                mn[qt][r] = fminf(fminf(mn[qt][r], aA[qt][r]), aB[qt][r]);  // -> v_min3
    }

    // ---- reduce: min across the 16 col-slots (lanes within 16-group), +a2, sum ----
    // D layout (m89): col = lane&15, row = (lane>>4)*4 + r
    float s = 0.f;
    #pragma unroll
    for (int qt = 0; qt < QT; ++qt) {
        #pragma unroll
        for (int r = 0; r < 4; ++r) {
            float v = mn[qt][r];
            v = fminf(v, __shfl_xor(v, 1, 64));
            v = fminf(v, __shfl_xor(v, 2, 64));
            v = fminf(v, __shfl_xor(v, 4, 64));
            v = fminf(v, __shfl_xor(v, 8, 64));
            s += v + qs[(wid*QT + qt)*16 + lg*4 + r].w;
        }
    }
    // s replicated within each 16-lane group; sum the 4 distinct group values
    s += __shfl_xor(s, 16, 64);
    s += __shfl_xor(s, 32, 64);
    if (lane == 0) wsum[wid] = s;
    __syncthreads();
    if (tid == 0) partial[blk] = (wsum[0] + wsum[1]) + (wsum[2] + wsum[3]);
}

__global__ __launch_bounds__(256) void finalize_kernel(
    const float* __restrict__ partial, const float* __restrict__ pred,
    const int* __restrict__ gt, float* __restrict__ out)
{
    __shared__ float s_ce[BATCH];
    __shared__ float wsum[4];
    const int tid = threadIdx.x;

    float v = partial[tid] + partial[tid + 256];
    #pragma unroll
    for (int o = 32; o > 0; o >>= 1) v += __shfl_down(v, o, 64);
    const int lane = tid & 63, wid = tid >> 6;
    if (lane == 0) wsum[wid] = v;

    if (tid < BATCH) {
        const float* row = pred + tid * NUM_CLASSES;
        float mx = row[0];
        #pragma unroll
        for (int c = 1; c < NUM_CLASSES; ++c) mx = fmaxf(mx, row[c]);
        float se = 0.f;
        #pragma unroll
        for (int c = 0; c < NUM_CLASSES; ++c) se += __expf(row[c] - mx);
        const int lbl = gt[tid];
        s_ce[tid] = -(row[lbl] - mx - __logf(se));
    }
    __syncthreads();

    if (tid == 0) {
        float cd_sum = (wsum[0] + wsum[1]) + (wsum[2] + wsum[3]);
        float cd = cd_sum / (float)(BATCH * NPTS);
        float ce = 0.f;
        for (int i = 0; i < BATCH; ++i) ce += s_ce[i];
        ce /= (float)BATCH;
        out[0] = 5.f * cd + ce;
        out[1] = cd;
        out[2] = ce;
    }
}

extern "C" void kernel_launch(void* const* d_in, const int* in_sizes, int n_in,
                              void* d_out, int out_size, void* d_ws, size_t ws_size,
                              hipStream_t stream) {
    const float* inst  = (const float*)d_in[0];
    const float* model = (const float*)d_in[1];
    const float* pred  = (const float*)d_in[2];
    const int*   gt    = (const int*)d_in[3];
    float* out     = (float*)d_out;
    float* partial = (float*)d_ws;   // 512 floats

    chamfer_mfma<<<512, THREADS, 0, stream>>>(inst, model, partial);
    finalize_kernel<<<1, 256, 0, stream>>>(partial, pred, gt, out);
}

// Round 4
// 25.827 us; speedup vs baseline: 1.8435x; 1.0616x over previous
//
#include <hip/hip_runtime.h>

typedef __attribute__((ext_vector_type(8)))  short short8;
typedef __attribute__((ext_vector_type(16))) float f32x16;

#define NPTS 2048
#define BATCH 32
#define NUM_CLASSES 6
#define THREADS 256
#define QT 2            // query tiles (32 rows) per wave; block = 4 waves * 64 q = 256 q
#define CTILES 64       // 2048 / 32 candidates per tile
// grid = 2 dirs * 32 batches * 8 qchunks = 512 blocks

#define BF16_ONE ((short)0x3F80)

__device__ __forceinline__ unsigned short f2bf(float x) {
    union { float f; unsigned u; } v; v.f = x;
    unsigned r = v.u + 0x7FFF + ((v.u >> 16) & 1);   // RNE to bf16
    return (unsigned short)(r >> 16);
}
__device__ __forceinline__ float bf2f(unsigned short h) {
    union { unsigned u; float f; } v; v.u = ((unsigned)h) << 16; return v.f;
}

// K-slot plan (K=16), D = a2 + b2 - 2 a.b exactly tiled:
//  k0-2 : A=ah(x,y,z)  B=-2bh(x,y,z)
//  k3-5 : A=al(x,y,z)  B=-2bh(x,y,z)
//  k6-8 : A=ah(x,y,z)  B=-2bl(x,y,z)
//  k9   : A=1          B=b2h
//  k10  : A=1          B=b2l
//  k11  : A=a2h        B=1
//  k12  : A=a2l        B=1
//  k13-15: 0
__global__ __launch_bounds__(THREADS) void chamfer_mfma32(
    const float* __restrict__ inst, const float* __restrict__ model,
    float* __restrict__ partial)
{
    __shared__ char  cands[NPTS * 32];   // 64 KB: per cand 16B kg0(k0-7) + 16B kg1(k8-15)
    __shared__ float wsum[4];

    const int blk   = blockIdx.x;
    const int dir   = blk >> 8;
    const int batch = (blk >> 3) & 31;
    const int qc    = blk & 7;
    const int tid   = threadIdx.x;
    const int lane  = tid & 63, wid = tid >> 6;
    const int lh    = lane >> 5, lr = lane & 31;

    const float* __restrict__ Q = dir ? model : inst;
    const float* __restrict__ C = dir ? inst  : model;

    // ---- stage candidates into B-frag layout ----
    const float* cb = C + (size_t)batch * NPTS * 3;
    for (int c = tid; c < NPTS; c += THREADS) {
        float bx = cb[c*3+0], by = cb[c*3+1], bz = cb[c*3+2];
        float m2x = -2.f*bx, m2y = -2.f*by, m2z = -2.f*bz;
        unsigned short hx = f2bf(m2x), hy = f2bf(m2y), hz = f2bf(m2z);
        unsigned short lx = f2bf(m2x - bf2f(hx));
        unsigned short ly = f2bf(m2y - bf2f(hy));
        unsigned short lz = f2bf(m2z - bf2f(hz));
        float b2 = fmaf(bx,bx, fmaf(by,by, bz*bz));
        unsigned short b2h = f2bf(b2);
        unsigned short b2l = f2bf(b2 - bf2f(b2h));
        short8 kg0 = { (short)hx,(short)hy,(short)hz,(short)hx,(short)hy,(short)hz,(short)lx,(short)ly };
        short8 kg1 = { (short)lz,(short)b2h,(short)b2l, BF16_ONE, BF16_ONE, 0,0,0 };
        *(short8*)(cands + c*32)      = kg0;
        *(short8*)(cands + c*32 + 16) = kg1;
    }

    // ---- A-frags from global (row = lane&31, k = (lane>>5)*8 + j) ----
    short8 af[QT];
    const float* qb = Q + ((size_t)batch * NPTS + (size_t)qc * 256) * 3;
    #pragma unroll
    for (int qt = 0; qt < QT; ++qt) {
        const int qi = (wid * QT + qt) * 32 + lr;
        float x = qb[qi*3+0], y = qb[qi*3+1], z = qb[qi*3+2];
        unsigned short hx = f2bf(x), hy = f2bf(y), hz = f2bf(z);
        unsigned short lx = f2bf(x - bf2f(hx));
        unsigned short ly = f2bf(y - bf2f(hy));
        unsigned short lz = f2bf(z - bf2f(hz));
        float a2 = fmaf(x,x, fmaf(y,y, z*z));
        unsigned short a2h = f2bf(a2);
        unsigned short a2l = f2bf(a2 - bf2f(a2h));
        if (lh == 0)
            af[qt] = (short8){ (short)hx,(short)hy,(short)hz,(short)lx,(short)ly,(short)lz,(short)hx,(short)hy };
        else
            af[qt] = (short8){ (short)hz, BF16_ONE, BF16_ONE, (short)a2h,(short)a2l, 0,0,0 };
    }
    __syncthreads();

    // ---- main loop: B-frag read is conflict-free (64 lanes cover 1024B tile once) ----
    f32x16 mn;
    #pragma unroll
    for (int r = 0; r < 16; ++r) mn[r] = 3.4e38f;
    f32x16 mn2 = mn;
    const f32x16 zero16 = mn - mn;   // 0.0f x16 (3.4e38-3.4e38 = 0)

    int boff = lr * 32 + lh * 16;
    for (int ct = 0; ct < CTILES; ct += 2) {
        short8 b0 = *(const short8*)(cands + boff);
        short8 b1 = *(const short8*)(cands + boff + 1024);
        boff += 2048;
        f32x16 a00 = __builtin_amdgcn_mfma_f32_32x32x16_bf16(af[0], b0, zero16, 0,0,0);
        f32x16 a10 = __builtin_amdgcn_mfma_f32_32x32x16_bf16(af[1], b0, zero16, 0,0,0);
        f32x16 a01 = __builtin_amdgcn_mfma_f32_32x32x16_bf16(af[0], b1, zero16, 0,0,0);
        f32x16 a11 = __builtin_amdgcn_mfma_f32_32x32x16_bf16(af[1], b1, zero16, 0,0,0);
        #pragma unroll
        for (int r = 0; r < 16; ++r) mn[r]  = fminf(fminf(a00[r], a01[r]), mn[r]);   // v_min3
        #pragma unroll
        for (int r = 0; r < 16; ++r) mn2[r] = fminf(fminf(a10[r], a11[r]), mn2[r]);
    }

    // ---- epilogue: min across 32 candidate-cols (lanes within 32-group), sum ----
    float s = 0.f;
    #pragma unroll
    for (int r = 0; r < 16; ++r) {
        float v = mn[r];
        v = fminf(v, __shfl_xor(v, 1, 64));
        v = fminf(v, __shfl_xor(v, 2, 64));
        v = fminf(v, __shfl_xor(v, 4, 64));
        v = fminf(v, __shfl_xor(v, 8, 64));
        v = fminf(v, __shfl_xor(v, 16, 64));
        s += v;
        float w = mn2[r];
        w = fminf(w, __shfl_xor(w, 1, 64));
        w = fminf(w, __shfl_xor(w, 2, 64));
        w = fminf(w, __shfl_xor(w, 4, 64));
        w = fminf(w, __shfl_xor(w, 8, 64));
        w = fminf(w, __shfl_xor(w, 16, 64));
        s += w;
    }
    s += __shfl_xor(s, 32, 64);      // combine lh=0 / lh=1 query halves
    if (lane == 0) wsum[wid] = s;
    __syncthreads();
    if (tid == 0) partial[blk] = (wsum[0] + wsum[1]) + (wsum[2] + wsum[3]);
}

__global__ __launch_bounds__(256) void finalize_kernel(
    const float* __restrict__ partial, const float* __restrict__ pred,
    const int* __restrict__ gt, float* __restrict__ out)
{
    __shared__ float s_ce[BATCH];
    __shared__ float wsum[4];
    const int tid = threadIdx.x;

    float v = partial[tid] + partial[tid + 256];
    #pragma unroll
    for (int o = 32; o > 0; o >>= 1) v += __shfl_down(v, o, 64);
    const int lane = tid & 63, wid = tid >> 6;
    if (lane == 0) wsum[wid] = v;

    if (tid < BATCH) {
        const float* row = pred + tid * NUM_CLASSES;
        float mx = row[0];
        #pragma unroll
        for (int c = 1; c < NUM_CLASSES; ++c) mx = fmaxf(mx, row[c]);
        float se = 0.f;
        #pragma unroll
        for (int c = 0; c < NUM_CLASSES; ++c) se += __expf(row[c] - mx);
        const int lbl = gt[tid];
        s_ce[tid] = -(row[lbl] - mx - __logf(se));
    }
    __syncthreads();

    if (tid == 0) {
        float cd_sum = (wsum[0] + wsum[1]) + (wsum[2] + wsum[3]);
        float cd = cd_sum / (float)(BATCH * NPTS);
        float ce = 0.f;
        for (int i = 0; i < BATCH; ++i) ce += s_ce[i];
        ce /= (float)BATCH;
        out[0] = 5.f * cd + ce;
        out[1] = cd;
        out[2] = ce;
    }
}

extern "C" void kernel_launch(void* const* d_in, const int* in_sizes, int n_in,
                              void* d_out, int out_size, void* d_ws, size_t ws_size,
                              hipStream_t stream) {
    const float* inst  = (const float*)d_in[0];
    const float* model = (const float*)d_in[1];
    const float* pred  = (const float*)d_in[2];
    const int*   gt    = (const int*)d_in[3];
    float* out     = (float*)d_out;
    float* partial = (float*)d_ws;   // 512 floats

    chamfer_mfma32<<<512, THREADS, 0, stream>>>(inst, model, partial);
    finalize_kernel<<<1, 256, 0, stream>>>(partial, pred, gt, out);
}